// Round 5
// baseline (879.592 us; speedup 1.0000x reference)
//
#include <hip/hip_runtime.h>
#include <stdint.h>

#define LM1  127
#define NTHR 512

typedef _Float16 half8_t __attribute__((ext_vector_type(8)));
typedef _Float16 half4_t __attribute__((ext_vector_type(4)));
typedef float    f32x4   __attribute__((ext_vector_type(4)));
typedef float    f32x2   __attribute__((ext_vector_type(2)));

__device__ __forceinline__ float fast_tanh(float x) {
  float e = __expf(2.0f * x);
  return 1.0f - 2.0f * __builtin_amdgcn_rcpf(e + 1.0f);
}

// Round-5 = round-4 structure (ONE barrier + ONE cross-wave handoff per
// sub-stage) with two correctness fixes:
//  (1) permlane combine: copy forced INSIDE the asm with an early-clobber
//      scratch reg -- the round-4 form (two "+v" fed from the same value)
//      lets the allocator coalesce a==b, turning the swap into a self-swap
//      (kc = 2x partner half instead of self+partner).
//  (2) __syncthreads() between the zero/staging loops and the z0 section:
//      round 4 raced z0's zsbT[0] writes against other waves' zero-init.
// Structure recap:
//  - GEMM1 redundant per wave, operand-swapped: D1 = mfma(W1^T Afrag, z^T Bfrag)
//    -> h^T lands with batch row in lane&15, h-index in regs; hA handoff to
//    GEMM2's A-frag is a WITHIN-WAVE private-LDS bounce (no barrier).
//  - u = t*W1[0] + b1 applied in f32 (ubuf dbuf, staged one stage ahead).
//  - zsbT (z^T B-frag layout) double-buffered; single lgkm-only barrier/stage.
#define BAR() asm volatile("s_waitcnt lgkmcnt(0)\n\ts_barrier" ::: "memory")

__global__ void __launch_bounds__(NTHR, 2) cde_kernel(
    const float* __restrict__ coeffs,
    const float* __restrict__ Wi1, const float* __restrict__ bi1,
    const float* __restrict__ Wi2, const float* __restrict__ bi2,
    const float* __restrict__ W1,  const float* __restrict__ b1,
    const float* __restrict__ W2,  const float* __restrict__ b2,
    float* __restrict__ out)
{
  __shared__ __align__(16) _Float16 wlds[8192];      // 16 KB: W1^T A-frags [(2m+kt)*512 + 8L + j]
  __shared__ __align__(16) _Float16 zsbT[2][1024];   //  4 KB: z^T B-frag layout, dbuf
  __shared__ __align__(16) _Float16 hA[8][2048];     // 32 KB: per-wave h^T scratch (A-frag layout)
  __shared__ __align__(16) float    fwb[8][288];     //  9 KB: word(cl,r) = 36*(cl>>3)+4*(cl&7)+r
  __shared__ __align__(16) float    gds[2][3][4][8]; // dXdt at fr=0,.5,1 (dbuf)
  __shared__ __align__(16) float    ubuf[2][128];    //  1 KB: u = t*W1_0 + b1 (dbuf)

  const int t    = threadIdx.x;
  const int lane = t & 63;
  const int w    = t >> 6;            // wave 0..7
  const int l15  = lane & 15;
  const int lq   = lane >> 4;
  const int row0 = blockIdx.x * 4;

  // zero zsbT once (rows r=4..15 stay zero forever -> garbage lanes read 0)
  for (int u = t; u < 1024; u += NTHR) ((uint32_t*)zsbT)[u] = 0u;

  // stage W1^T A-frags: value (c = 16m + L&15, k = 8*(L>>4)+j+32kt) = W1[1+k][c]
  for (int idx = t; idx < 8192; idx += NTHR) {
    const int m = idx >> 10, kt = (idx >> 9) & 1, L = (idx >> 3) & 63, j = idx & 7;
    wlds[idx] = (_Float16)W1[(1 + 8 * (L >> 4) + j + 32 * kt) * 128 + 16 * m + (L & 15)];
  }

  __syncthreads();   // fix (2): init-zero/staging complete BEFORE z0 writes zsbT[0]

  // ---- W2 -> B-fragments: 4 n-tiles x 4 k-tiles (cols 64w + nt*16 + l15)
  half8_t bf[4][4];
  #pragma unroll
  for (int nt = 0; nt < 4; ++nt)
    #pragma unroll
    for (int kt = 0; kt < 4; ++kt)
      #pragma unroll
      for (int j = 0; j < 8; ++j)
        bf[nt][kt][j] =
            (_Float16)W2[(kt * 32 + lq * 8 + j) * 512 + w * 64 + nt * 16 + l15];

  // ---- wave-0 u staging constants + ubuf[0] init (t=0 -> u = b1)
  float w10a = 0.f, w10b = 0.f, b1a = 0.f, b1b = 0.f;
  if (w == 0) {
    w10a = W1[2 * lane]; w10b = W1[2 * lane + 1];
    b1a  = b1[2 * lane]; b1b  = b1[2 * lane + 1];
    f32x2 u0 = {b1a, b1b};
    *(f32x2*)&ubuf[0][2 * lane] = u0;
  }

  // ---- kc constants: lane = cp*32 + hh*4 + r, in-lane c = 4cp+cc
  const int r_ = lane & 3;
  const int hh = (lane >> 2) & 7;
  const int cp = lane >> 5;
  const float* bp = b2 + w * 64 + hh * 8 + cp * 4;
  const float b2c0 = bp[0], b2c1 = bp[1], b2c2 = bp[2], b2c3 = bp[3];
  const int frbase = 36 * hh + 16 * cp + r_;
  const int hx = 8 * w + hh;                 // owner h-col (lanes 0..31)
  // owner zsbT slot (halfs, within one buffer): value (k=hx, row=r_)
  const int zoff = 8 * r_ + 128 * ((hx >> 3) & 3) + 512 * (hx >> 5) + (hx & 7);
  float* const fsp = &fwb[w][36 * (l15 >> 3) + 4 * (l15 & 7)];

  // hA (private) addressing: write base for packed quad (c=16m+4lq+reg, row=l15)
  _Float16* const hAw = &hA[w][0];
  const int hbase = 8 * l15 + 4 * (lq & 1) + 128 * (lq >> 1);  // + 256*m per m-tile

  // ---- z0 (owners: lanes 0..31 of each wave)
  float z = 0.0f;
  if (lane < 32) {
    const float* cb = coeffs + (size_t)(row0 + r_) * (LM1 * 32);
    float x0[8];
    #pragma unroll
    for (int c = 0; c < 8; ++c) x0[c] = cb[c];
    float acc = bi2[hx];
    for (int j = 0; j < 20; ++j) {
      float u = bi1[j];
      #pragma unroll
      for (int c = 0; c < 8; ++c) u += x0[c] * Wi1[c * 20 + j];
      acc += fmaxf(u, 0.0f) * Wi2[j * 64 + hx];
    }
    z = fast_tanh(acc);
    zsbT[0][zoff] = (_Float16)z;
    out[(size_t)(row0 + r_) * 8192 + hx] = z;
  }

  // ---- coeff prefetch / gds staging on wave 7
  const int rg = (lane >> 3) & 3, cg = lane & 7;
  const float* cbp = coeffs + (size_t)(row0 + rg) * (LM1 * 32);
  const bool stg = (w == 7) && (lane < 32);
  float pb2 = 0.f, pc2 = 0.f, pd2 = 0.f, pbn2 = 0.f;
  if (stg) {
    const float pb = cbp[8 + cg], pc = cbp[16 + cg], pd = cbp[24 + cg], pbn = cbp[40 + cg];
    gds[0][0][rg][cg] = pb;
    gds[0][1][rg][cg] = pb + pc + 0.75f * pd;
    gds[0][2][rg][cg] = pbn;              // i=0 < LM1-1 always
  }

  __syncthreads();   // init complete (full barrier)

  for (int i = 0; i < LM1; ++i) {
    // issue next-interval coeff loads early; consumed at s==3 (vmem in flight)
    if (stg && i + 1 < LM1) {
      const float* nb = cbp + (size_t)(i + 1) * 32;
      pb2 = nb[8 + cg]; pc2 = nb[16 + cg]; pd2 = nb[24 + cg];
      pbn2 = (i + 2 < LM1) ? nb[40 + cg] : 0.0f;
    }

    float ksum = 0.0f;
    #pragma unroll
    for (int s = 0; s < 4; ++s) {
      const int rb   = s & 1;          // read buffer (zsbT, ubuf)
      const int wbuf = rb ^ 1;         // write buffer
      const int gi   = (s == 0) ? 0 : (s == 3) ? 2 : 1;
      const float tnext = (float)i + ((s < 2) ? 0.5f : 1.0f);  // t of stage s+1

      // z^T B-frags (conflict-free at 8*lane) + dXdt (hoisted)
      const half8_t zb0 = *(const half8_t*)(&zsbT[rb][8 * lane]);
      const half8_t zb1 = *(const half8_t*)(&zsbT[rb][8 * lane + 512]);
      const f32x4 gv = *(const f32x4*)&gds[i & 1][gi][r_][4 * cp];

      // GEMM1 (redundant per wave, swapped): D1 rows = h-cols 16m+4lq+reg, col = l15
      #pragma unroll
      for (int m = 0; m < 8; ++m) {
        const half8_t af0 = *(const half8_t*)(&wlds[(2 * m    ) * 512 + 8 * lane]);
        const half8_t af1 = *(const half8_t*)(&wlds[(2 * m + 1) * 512 + 8 * lane]);
        f32x4 acc = {0.f, 0.f, 0.f, 0.f};
        acc = __builtin_amdgcn_mfma_f32_16x16x32_f16(af0, zb0, acc, 0, 0, 0);
        acc = __builtin_amdgcn_mfma_f32_16x16x32_f16(af1, zb1, acc, 0, 0, 0);
        const f32x4 uv = *(const f32x4*)&ubuf[rb][16 * m + 4 * lq];  // broadcast
        half4_t hv;
        hv[0] = (_Float16)fmaxf(acc.x + uv.x, 0.0f);
        hv[1] = (_Float16)fmaxf(acc.y + uv.y, 0.0f);
        hv[2] = (_Float16)fmaxf(acc.z + uv.z, 0.0f);
        hv[3] = (_Float16)fmaxf(acc.w + uv.w, 0.0f);
        *(half4_t*)(hAw + hbase + 256 * m) = hv;   // b64, bank-optimal
      }
      asm volatile("s_waitcnt lgkmcnt(0)" ::: "memory");  // within-wave hA handoff

      // GEMM2 (sliced): f-cols [64w, 64w+64)
      half8_t ha[4];
      #pragma unroll
      for (int kt = 0; kt < 4; ++kt)
        ha[kt] = *(const half8_t*)(hAw + 8 * lane + 512 * kt);
      f32x4 d0 = {0.f, 0.f, 0.f, 0.f}, d1 = d0, d2 = d0, d3 = d0;
      #pragma unroll
      for (int kt = 0; kt < 4; ++kt) {
        d0 = __builtin_amdgcn_mfma_f32_16x16x32_f16(ha[kt], bf[0][kt], d0, 0, 0, 0);
        d1 = __builtin_amdgcn_mfma_f32_16x16x32_f16(ha[kt], bf[1][kt], d1, 0, 0, 0);
        d2 = __builtin_amdgcn_mfma_f32_16x16x32_f16(ha[kt], bf[2][kt], d2, 0, 0, 0);
        d3 = __builtin_amdgcn_mfma_f32_16x16x32_f16(ha[kt], bf[3][kt], d3, 0, 0, 0);
      }
      if (lane < 16) {
        *(f32x4*)(fsp)       = d0;
        *(f32x4*)(fsp + 72)  = d1;
        *(f32x4*)(fsp + 144) = d2;
        *(f32x4*)(fsp + 216) = d3;
      }
      asm volatile("s_waitcnt lgkmcnt(0)" ::: "memory");  // within-wave fwb handoff

      // kc: 4 in-lane channels; cross-half combine on the VALU pipe.
      // fix (1): copy emitted INSIDE the asm; "=&v" guarantees b != a's reg.
      const float* fb = &fwb[w][frbase];
      const float v0 = fb[0], v1 = fb[4], v2 = fb[8], v3 = fb[12];
      float kcv = fast_tanh(v0 + b2c0) * gv.x + fast_tanh(v1 + b2c1) * gv.y
                + fast_tanh(v2 + b2c2) * gv.z + fast_tanh(v3 + b2c3) * gv.w;
      {
        int a = __float_as_int(kcv), b;
        asm volatile("v_mov_b32 %1, %0\n\t"
                     "v_permlane32_swap_b32 %0, %1"
                     : "+v"(a), "=&v"(b));
        kcv = __int_as_float(a) + __int_as_float(b);
      }
      ksum += ((s == 1 || s == 2) ? 2.0f : 1.0f) * kcv;

      // stage u for next stage (wave 0)
      if (w == 0) {
        f32x2 un = {fmaf(tnext, w10a, b1a), fmaf(tnext, w10b, b1b)};
        *(f32x2*)&ubuf[wbuf][2 * lane] = un;
      }
      // owners stage z for next stage into the other buffer
      if (s < 3) {
        const float cn = (s == 2) ? 1.0f : 0.5f;
        if (lane < 32) zsbT[wbuf][zoff] = (_Float16)(z + cn * kcv);
      } else {
        if (lane < 32) {
          z = fmaf(ksum, 1.0f / 6.0f, z);
          zsbT[wbuf][zoff] = (_Float16)z;
          out[(size_t)(row0 + r_) * 8192 + (size_t)(i + 1) * 64 + hx] = z;  // fire-and-forget
        }
        if (stg && i + 1 < LM1) {   // write gds for step i+1 (other parity)
          const int ii = i + 1;
          gds[ii & 1][0][rg][cg] = pb2;
          gds[ii & 1][1][rg][cg] = pb2 + pc2 + 0.75f * pd2;
          gds[ii & 1][2][rg][cg] =
              (ii < LM1 - 1) ? pbn2 : fmaf(3.0f, pd2, fmaf(2.0f, pc2, pb2));
        }
      }
      BAR();   // the single per-sub-stage barrier (lgkm-only)
    }
  }
}

extern "C" void kernel_launch(void* const* d_in, const int* in_sizes, int n_in,
                              void* d_out, int out_size, void* d_ws, size_t ws_size,
                              hipStream_t stream) {
  const float* coeffs = (const float*)d_in[0];
  const float* Wi1    = (const float*)d_in[1];
  const float* bi1    = (const float*)d_in[2];
  const float* Wi2    = (const float*)d_in[3];
  const float* bi2    = (const float*)d_in[4];
  const float* W1     = (const float*)d_in[5];
  const float* b1     = (const float*)d_in[6];
  const float* W2     = (const float*)d_in[7];
  const float* b2     = (const float*)d_in[8];
  float* out          = (float*)d_out;
  (void)in_sizes; (void)n_in; (void)out_size; (void)d_ws; (void)ws_size;
  cde_kernel<<<256, NTHR, 0, stream>>>(coeffs, Wi1, bi1, Wi2, bi2,
                                       W1, b1, W2, b2, out);
}

// Round 6
// 603.597 us; speedup vs baseline: 1.4573x; 1.4573x over previous
//
#include <hip/hip_runtime.h>
#include <stdint.h>

#define LM1  127
#define NTHR 256

typedef _Float16 half8_t __attribute__((ext_vector_type(8)));
typedef float    f32x4   __attribute__((ext_vector_type(4)));

__device__ __forceinline__ float fast_tanh(float x) {
  float e = __expf(2.0f * x);
  return 1.0f - 2.0f * __builtin_amdgcn_rcpf(e + 1.0f);
}

// Round-6: LDS-pipe-occupancy model (confirmed by r5's failure: +128 b128/CU
// -> +1700 cyc). Per-CU LDS ops scale with #waves (broadcast reads + kc ops
// are per-wave). So: 4 waves instead of 8, each owning 2x wider slices.
//   wave w: phase B h-cols [32w,32w+32) (2 nt), phase C f-cols [128w,128w+128)
//   (8 nt, bf[8][4]=128 VGPR). MFMA/substage unchanged (144).
// kc: 4 waves x 64 lanes = 256 owners = all (row r, h hx) pairs -> each lane
// owns one (r_,hx) with ALL 8 channels in-lane: no cross-lane combine, g read
// is 2 contiguous f32x4. fwb layout [8 grp][68] (group-padded): writes and
// reads both 2-way bank aliasing (free).
// Barriers: lgkm-only (r3-verified); out[] stores fire-and-forget; coeff
// prefetch stays in flight across barriers.
#define BAR() asm volatile("s_waitcnt lgkmcnt(0)\n\ts_barrier" ::: "memory")

__global__ void __launch_bounds__(NTHR, 1) cde_kernel(
    const float* __restrict__ coeffs,
    const float* __restrict__ Wi1, const float* __restrict__ bi1,
    const float* __restrict__ Wi2, const float* __restrict__ bi2,
    const float* __restrict__ W1,  const float* __restrict__ b1,
    const float* __restrict__ W2,  const float* __restrict__ b2,
    float* __restrict__ out)
{
  __shared__ __align__(16) _Float16 zsb[1024];       // 2 KB: chunk = kh*64 + lq*16 + m
  __shared__ __align__(16) _Float16 hA [2048];       // 4 KB: chunk = kt*64 + lq*16 + m
  __shared__ __align__(16) float    fwb[4][544];     // 8.5 KB: [wave][grp*68 + 4*lc + r]
  __shared__ __align__(16) float    gds[2][3][4][8]; // dXdt at fr=0,.5,1 (dbuf)

  const int t    = threadIdx.x;
  const int lane = t & 63;
  const int w    = t >> 6;            // wave 0..3
  const int l15  = lane & 15;
  const int lq   = lane >> 4;
  const int row0 = blockIdx.x * 4;

  // zero staging buffers once (rows m>=4 stay zero)
  for (int u = t; u < 512;  u += NTHR) ((uint32_t*)zsb)[u] = 0u;
  for (int u = t; u < 1024; u += NTHR) ((uint32_t*)hA)[u]  = 0u;

  // ---- W1 -> B-fragments: 2 n-tiles (h-cols 32w + 16nt + l15)
  half8_t bB[2][2];
  float w1t_c[2], b1_c[2];
  #pragma unroll
  for (int nt = 0; nt < 2; ++nt) {
    #pragma unroll
    for (int kt = 0; kt < 2; ++kt)
      #pragma unroll
      for (int j = 0; j < 8; ++j)
        bB[nt][kt][j] =
            (_Float16)W1[(1 + kt * 32 + lq * 8 + j) * 128 + 32 * w + 16 * nt + l15];
    w1t_c[nt] = W1[32 * w + 16 * nt + l15];
    b1_c[nt]  = b1[32 * w + 16 * nt + l15];
  }
  _Float16* hwp[2];                    // hA write bases (epilogue, lanes<16)
  #pragma unroll
  for (int nt = 0; nt < 2; ++nt) {
    const int col = 32 * w + 16 * nt + l15;
    const int ktw = (col >> 5) & 3, lqw2 = (col >> 3) & 3, j2 = col & 7;
    hwp[nt] = &hA[8 * (ktw * 64 + lqw2 * 16) + j2];
  }

  // ---- W2 -> B-fragments: 8 n-tiles x 4 k-tiles (cols 128w + nt*16 + l15)
  half8_t bf[8][4];
  #pragma unroll
  for (int nt = 0; nt < 8; ++nt)
    #pragma unroll
    for (int kt = 0; kt < 4; ++kt)
      #pragma unroll
      for (int j = 0; j < 8; ++j)
        bf[nt][kt][j] =
            (_Float16)W2[(kt * 32 + lq * 8 + j) * 512 + 128 * w + nt * 16 + l15];

  // ---- owner map: every lane owns (r_ = lane&3, hx = 16w + (lane>>2))
  const int r_ = lane & 3;
  const int hh = lane >> 2;            // 0..15
  const int hx = 16 * w + hh;          // h index 0..63
  const float* b2p = b2 + 8 * hx;
  const f32x4 b2lo = *(const f32x4*)b2p;
  const f32x4 b2hi = *(const f32x4*)(b2p + 4);

  _Float16* zwp;                       // zsb write slot for this owner
  {
    const int kh = hx >> 5, lqw = (hx >> 3) & 3, jj = hx & 7;
    zwp = &zsb[8 * (kh * 64 + lqw * 16 + r_) + jj];
  }
  float* const fsp = &fwb[w][4 * l15];                      // write base (+68*nt)
  const float* const frp = &fwb[w][68 * (hh >> 1) + 32 * (hh & 1) + r_];  // read base (+4c)

  // ---- z0 (all 64 lanes are owners)
  float z;
  {
    const float* cb = coeffs + (size_t)(row0 + r_) * (LM1 * 32);
    float x0[8];
    #pragma unroll
    for (int c = 0; c < 8; ++c) x0[c] = cb[c];
    float acc = bi2[hx];
    for (int j = 0; j < 20; ++j) {
      float u = bi1[j];
      #pragma unroll
      for (int c = 0; c < 8; ++c) u += x0[c] * Wi1[c * 20 + j];
      acc += fmaxf(u, 0.0f) * Wi2[j * 64 + hx];
    }
    z = fast_tanh(acc);
    out[(size_t)(row0 + r_) * 8192 + hx] = z;
  }

  // ---- coeff prefetch / gds staging on wave 3: rg = (lane>>3)&3, cg = lane&7
  const int rg = (lane >> 3) & 3, cg = lane & 7;
  const float* cbp = coeffs + (size_t)(row0 + rg) * (LM1 * 32);
  float pb = 0.f, pc = 0.f, pd = 0.f, pbn = 0.f;
  const bool stg = (w == 3) && (lane < 32);
  if (stg) { pb = cbp[8 + cg]; pc = cbp[16 + cg]; pd = cbp[24 + cg]; pbn = cbp[40 + cg]; }

  __syncthreads();   // init-zero + staging complete (full barrier, once)

  for (int i = 0; i < LM1; ++i) {
    if (stg) {
      gds[i & 1][0][rg][cg] = pb;
      gds[i & 1][1][rg][cg] = pb + pc + 0.75f * pd;
      gds[i & 1][2][rg][cg] = (i < LM1 - 1) ? pbn : fmaf(3.0f, pd, fmaf(2.0f, pc, pb));
      if (i + 1 < LM1) {
        const float* nb = cbp + (size_t)(i + 1) * 32;
        pb = nb[8 + cg]; pc = nb[16 + cg]; pd = nb[24 + cg];
        pbn = (i + 2 < LM1) ? nb[40 + cg] : 0.0f;
      }
    }

    float ksum = 0.0f, kprev = 0.0f;
    #pragma unroll
    for (int s = 0; s < 4; ++s) {
      const float coef = (s == 0) ? 0.0f : (s == 3) ? 1.0f : 0.5f;
      const float ts   = (float)i + ((s == 0) ? 0.0f : (s == 3) ? 1.0f : 0.5f);
      const int   gi   = (s == 0) ? 0 : (s == 3) ? 2 : 1;

      // Phase A: all 64 owner-lanes stage zs (1 op/wave)
      *zwp = (_Float16)(z + coef * kprev);
      BAR();   // zsb (+ gds at s=0) visible

      // Phase B: h-cols [32w,32w+32), reads at 8*lane (conflict-free)
      {
        const half8_t a0 = *(const half8_t*)(zsb + 8 * lane);
        const half8_t a1 = *(const half8_t*)(zsb + 512 + 8 * lane);
        f32x4 hd[2];
        #pragma unroll
        for (int nt = 0; nt < 2; ++nt) {
          f32x4 acc = {0.f, 0.f, 0.f, 0.f};
          acc = __builtin_amdgcn_mfma_f32_16x16x32_f16(a0, bB[nt][0], acc, 0, 0, 0);
          acc = __builtin_amdgcn_mfma_f32_16x16x32_f16(a1, bB[nt][1], acc, 0, 0, 0);
          hd[nt] = acc;
        }
        if (lane < 16) {
          #pragma unroll
          for (int nt = 0; nt < 2; ++nt) {
            const float hb = fmaf(ts, w1t_c[nt], b1_c[nt]);
            hwp[nt][0]  = (_Float16)fmaxf(hd[nt].x + hb, 0.0f);
            hwp[nt][8]  = (_Float16)fmaxf(hd[nt].y + hb, 0.0f);
            hwp[nt][16] = (_Float16)fmaxf(hd[nt].z + hb, 0.0f);
            hwp[nt][24] = (_Float16)fmaxf(hd[nt].w + hb, 0.0f);
          }
        }
      }
      BAR();   // hA visible

      // Phase C: f-cols [128w,128w+128), then in-lane kc
      {
        const f32x4 gva = *(const f32x4*)&gds[i & 1][gi][r_][0];
        const f32x4 gvb = *(const f32x4*)&gds[i & 1][gi][r_][4];

        half8_t ha[4];
        #pragma unroll
        for (int kt = 0; kt < 4; ++kt)
          ha[kt] = *(const half8_t*)(hA + 8 * lane + 512 * kt);
        f32x4 d[8];
        #pragma unroll
        for (int nt = 0; nt < 8; ++nt) d[nt] = (f32x4){0.f, 0.f, 0.f, 0.f};
        #pragma unroll
        for (int kt = 0; kt < 4; ++kt)
          #pragma unroll
          for (int nt = 0; nt < 8; ++nt)
            d[nt] = __builtin_amdgcn_mfma_f32_16x16x32_f16(ha[kt], bf[nt][kt], d[nt], 0, 0, 0);
        if (lane < 16) {
          #pragma unroll
          for (int nt = 0; nt < 8; ++nt)
            *(f32x4*)(fsp + 68 * nt) = d[nt];   // grp=nt, lc=l15: 2-way free
        }
        asm volatile("s_waitcnt lgkmcnt(0)" ::: "memory");  // within-wave fwb handoff

        // kc: 8 in-lane channels, no cross-lane combine
        float kcv = fast_tanh(frp[0]  + b2lo.x) * gva.x
                  + fast_tanh(frp[4]  + b2lo.y) * gva.y
                  + fast_tanh(frp[8]  + b2lo.z) * gva.z
                  + fast_tanh(frp[12] + b2lo.w) * gva.w
                  + fast_tanh(frp[16] + b2hi.x) * gvb.x
                  + fast_tanh(frp[20] + b2hi.y) * gvb.y
                  + fast_tanh(frp[24] + b2hi.z) * gvb.z
                  + fast_tanh(frp[28] + b2hi.w) * gvb.w;
        kprev = kcv;
        ksum += ((s == 1 || s == 2) ? 2.0f : 1.0f) * kcv;
      }
    }
    z += ksum * (1.0f / 6.0f);
    out[(size_t)(row0 + r_) * 8192 + (size_t)(i + 1) * 64 + hx] = z;  // fire-and-forget
  }
}

extern "C" void kernel_launch(void* const* d_in, const int* in_sizes, int n_in,
                              void* d_out, int out_size, void* d_ws, size_t ws_size,
                              hipStream_t stream) {
  const float* coeffs = (const float*)d_in[0];
  const float* Wi1    = (const float*)d_in[1];
  const float* bi1    = (const float*)d_in[2];
  const float* Wi2    = (const float*)d_in[3];
  const float* bi2    = (const float*)d_in[4];
  const float* W1     = (const float*)d_in[5];
  const float* b1     = (const float*)d_in[6];
  const float* W2     = (const float*)d_in[7];
  const float* b2     = (const float*)d_in[8];
  float* out          = (float*)d_out;
  (void)in_sizes; (void)n_in; (void)out_size; (void)d_ws; (void)ws_size;
  cde_kernel<<<256, NTHR, 0, stream>>>(coeffs, Wi1, bi1, Wi2, bi2,
                                       W1, b1, W2, b2, out);
}